// Round 1
// baseline (261.089 us; speedup 1.0000x reference)
//
#include <hip/hip_runtime.h>
#include <math.h>

// Problem constants
#define B_   64
#define N_   197
#define C_   768
#define H_   12
#define HD_  64
#define BH_  (B_ * H_)          // 768
#define M_   (B_ * N_)          // 12608

typedef _Float16 half8 __attribute__((ext_vector_type(8)));
typedef float    f32x4 __attribute__((ext_vector_type(4)));

// Workspace byte offsets (all 16B aligned)
#define XH_OFF   0u           // 12608*768 fp16      = 19,365,888 B
#define WQH_OFF  19365888u    // 2304*768 fp16       =  3,538,944 B
#define WPH_OFF  22904832u    // 768*768 fp16        =  1,179,648 B
#define QH_OFF   24084480u    // [bh][197][64] fp16  = 19,365,888 B
#define KH_OFF   43450368u    // [bh][197][64] fp16
#define VH_OFF   62816256u    // [bh][197][64] fp16
#define OH_OFF   82182144u    // [B][N][C] fp16      = 19,365,888 B
#define P0_OFF   101548032u   // [bh][196] fp32      =    602,112 B
#define WS_BYTES 102150144u

__device__ __forceinline__ half8 h8zero() {
    half8 z;
    #pragma unroll
    for (int i = 0; i < 8; ++i) z[i] = (_Float16)0;
    return z;
}

// async 16B global -> LDS (wave-uniform LDS base + lane*16; per-lane global addr)
__device__ __forceinline__ void async16(const _Float16* g, _Float16* l) {
    __builtin_amdgcn_global_load_lds(
        (const __attribute__((address_space(1))) void*)g,
        (__attribute__((address_space(3))) void*)l,
        16, 0, 0);
}

// ---------------------------------------------------------------------------
__global__ void k_ws_too_small(float* out, float ws_bytes) { out[0] = -ws_bytes; }

// ---------------------------------------------------------------------------
// fp32 -> fp16 bulk convert, all three tensors in one launch.
// i ranges: [0,1210368) x->Xh, [1210368,1431552) w_qkv->Wqh, [1431552,1505280) w_proj->Wph
__global__ __launch_bounds__(256) void k_cvt_all(const float* __restrict__ x,
                                                 const float* __restrict__ wq,
                                                 const float* __restrict__ wp,
                                                 _Float16* __restrict__ Xh,
                                                 _Float16* __restrict__ Wqh,
                                                 _Float16* __restrict__ Wph) {
    int i = blockIdx.x * blockDim.x + threadIdx.x;
    const float* src;
    _Float16*    dst;
    if (i < 1210368)      { src = x;  dst = Xh; }
    else if (i < 1431552) { src = wq; dst = Wqh; i -= 1210368; }
    else                  { src = wp; dst = Wph; i -= 1431552; }
    float4 f0 = *(const float4*)(src + (size_t)i * 8);
    float4 f1 = *(const float4*)(src + (size_t)i * 8 + 4);
    half8 h;
    h[0]=(_Float16)f0.x; h[1]=(_Float16)f0.y; h[2]=(_Float16)f0.z; h[3]=(_Float16)f0.w;
    h[4]=(_Float16)f1.x; h[5]=(_Float16)f1.y; h[6]=(_Float16)f1.z; h[7]=(_Float16)f1.w;
    *(half8*)(dst + (size_t)i * 8) = h;
}

// ---------------------------------------------------------------------------
// NT-GEMM core, fp16 inputs, m97-style global_load_lds staging (direct-to-LDS
// DMA, linear [128][32]-half tiles, 2-barrier loop). A-frag: lane holds
// A[m=lane&15][k=(lane>>4)*8+j]; C/D: col=lane&15, row=quad*4+reg.
__device__ __forceinline__ void mfma_nt_core_h(const _Float16* __restrict__ A,
                                               const _Float16* __restrict__ B,
                                               int M, int K, int m0, int n0,
                                               _Float16* As, _Float16* Bs,
                                               f32x4 (&acc)[4][4]) {
    const int tid  = threadIdx.x;
    const int wave = tid >> 6, lane = tid & 63;
    const int wr   = (wave >> 1) << 6;
    const int wc   = (wave & 1) << 6;
    const int ln   = lane & 15, kq = lane >> 4;

    // staging geometry: chunk ci = rd*256 + tid -> LDS byte ci*16
    //   row = ci>>2 (rd0: 0..63, rd1: 64..127), col halves = (ci&3)*8
    const int row0 = tid >> 2;
    const int ch0  = (tid & 3) << 3;
    int ar0 = m0 + row0;        if (ar0 >= M) ar0 = 0;   // clamp; garbage rows
    int ar1 = m0 + 64 + row0;   if (ar1 >= M) ar1 = 0;   // discarded in epilogue
    const _Float16* A0 = A + (size_t)ar0 * K + ch0;
    const _Float16* A1 = A + (size_t)ar1 * K + ch0;
    const _Float16* B0 = B + (size_t)(n0 + row0) * K + ch0;
    const _Float16* B1 = B + (size_t)(n0 + 64 + row0) * K + ch0;
    // wave-uniform LDS dest bases (halves): rd*2048 + wave*512; HW adds lane*16B
    _Float16* AsD = As + (wave << 9);
    _Float16* BsD = Bs + (wave << 9);

    for (int k0 = 0; k0 < K; k0 += 32) {
        __syncthreads();                   // prior frag reads done before overwrite
        async16(A0 + k0, AsD);
        async16(A1 + k0, AsD + 2048);
        async16(B0 + k0, BsD);
        async16(B1 + k0, BsD + 2048);
        __syncthreads();                   // compiler drains vmcnt(0) before barrier

        half8 af[4], bf[4];
        #pragma unroll
        for (int t = 0; t < 4; ++t) {
            af[t] = *(const half8*)&As[(wr + t * 16 + ln) * 32 + kq * 8];
            bf[t] = *(const half8*)&Bs[(wc + t * 16 + ln) * 32 + kq * 8];
        }
        #pragma unroll
        for (int i = 0; i < 4; ++i)
            #pragma unroll
            for (int j = 0; j < 4; ++j)
                acc[i][j] = __builtin_amdgcn_mfma_f32_16x16x32_f16(af[i], bf[j], acc[i][j], 0, 0, 0);
    }
}

// ---------------------------------------------------------------------------
// qkv = x @ w_qkv^T (fp16 MFMA); scatter epilogue -> Qh(x0.125)/Kh/Vh fp16
__global__ __launch_bounds__(256) void k_qkv_mfma(const _Float16* __restrict__ Xh,
                                                  const _Float16* __restrict__ Wq,
                                                  _Float16* __restrict__ Qh,
                                                  _Float16* __restrict__ Kh,
                                                  _Float16* __restrict__ Vh) {
    __shared__ _Float16 As[128 * 32];
    __shared__ _Float16 Bs[128 * 32];
    const int m0 = blockIdx.y << 7;
    const int n0 = blockIdx.x << 7;
    f32x4 acc[4][4] = {};
    mfma_nt_core_h(Xh, Wq, M_, C_, m0, n0, As, Bs, acc);

    const int lane = threadIdx.x & 63;
    const int wave = threadIdx.x >> 6;
    const int wr = (wave >> 1) << 6, wc = (wave & 1) << 6;
    const int ln = lane & 15, kq = lane >> 4;
    #pragma unroll
    for (int mt = 0; mt < 4; ++mt) {
        #pragma unroll
        for (int i = 0; i < 4; ++i) {
            const int m = m0 + wr + mt * 16 + kq * 4 + i;
            if (m >= M_) continue;
            const int b = m / N_;
            const int n = m - b * N_;
            #pragma unroll
            for (int nt = 0; nt < 4; ++nt) {
                const int d  = n0 + wc + nt * 16 + ln;
                const int t3 = d / C_;
                const int rr = d - t3 * C_;
                const int h  = rr >> 6;
                const int e  = rr & 63;
                const size_t off = ((size_t)((b * H_ + h) * N_ + n)) * HD_ + e;
                const float v = acc[mt][nt][i];
                if      (t3 == 0) Qh[off] = (_Float16)(v * 0.125f);
                else if (t3 == 1) Kh[off] = (_Float16)v;
                else              Vh[off] = (_Float16)v;
            }
        }
    }
}

// ---------------------------------------------------------------------------
// out = O @ w_proj^T + b_proj (fp16 MFMA, fp32 out)
__global__ __launch_bounds__(256) void k_proj_mfma(const _Float16* __restrict__ Oh,
                                                   const _Float16* __restrict__ Wp,
                                                   const float* __restrict__ bias,
                                                   float* __restrict__ out) {
    __shared__ _Float16 As[128 * 32];
    __shared__ _Float16 Bs[128 * 32];
    const int m0 = blockIdx.y << 7;
    const int n0 = blockIdx.x << 7;
    f32x4 acc[4][4] = {};
    mfma_nt_core_h(Oh, Wp, M_, C_, m0, n0, As, Bs, acc);

    const int lane = threadIdx.x & 63;
    const int wave = threadIdx.x >> 6;
    const int wr = (wave >> 1) << 6, wc = (wave & 1) << 6;
    const int ln = lane & 15, kq = lane >> 4;
    float bv[4];
    #pragma unroll
    for (int nt = 0; nt < 4; ++nt) bv[nt] = bias[n0 + wc + nt * 16 + ln];
    #pragma unroll
    for (int mt = 0; mt < 4; ++mt) {
        #pragma unroll
        for (int i = 0; i < 4; ++i) {
            const int m = m0 + wr + mt * 16 + kq * 4 + i;
            if (m >= M_) continue;
            #pragma unroll
            for (int nt = 0; nt < 4; ++nt)
                out[(size_t)m * C_ + n0 + wc + nt * 16 + ln] = acc[mt][nt][i] + bv[nt];
        }
    }
}

// ---------------------------------------------------------------------------
// Fused attention: per (row-tile rt of 64, bh): S=QK^T -> softmax -> O=PV.
// LDS: Ks 208x72 (S phase) aliased by Pl 4x16x232 (PV phase); Vt 64x232.
// Total 59,648 B static.
__global__ __launch_bounds__(256) void k_attn(const _Float16* __restrict__ Qh,
                                              const _Float16* __restrict__ Kh,
                                              const _Float16* __restrict__ Vh,
                                              _Float16* __restrict__ Oh,
                                              float* __restrict__ P0) {
    __shared__ _Float16 lds[29824];
    _Float16* Ks = lds;            // 208*72 = 14976 halves
    _Float16* Pl = lds;            // 4*16*232 = 14848 halves (aliases Ks)
    _Float16* Vt = lds + 14976;    // 64*232  = 14848 halves

    const int bh = blockIdx.y, rt = blockIdx.x;
    const int b = bh / H_, h = bh - b * H_;
    const int tid = threadIdx.x, wave = tid >> 6, lane = tid & 63;
    const int ln = lane & 15, kq = lane >> 4;
    const size_t kvb = (size_t)bh * N_ * HD_;

    // stage K rows -> Ks[key*72 + d]; keys 197..207 zeroed
    for (int idx = tid; idx < 208 * 8; idx += 256) {
        const int key = idx >> 3, c = (idx & 7) << 3;
        half8 v = (key < N_) ? *(const half8*)(Kh + kvb + (size_t)key * HD_ + c) : h8zero();
        *(half8*)&Ks[key * 72 + c] = v;
    }
    // stage V transposed -> Vt[d*232 + key]
    for (int idx = tid; idx < 197 * 8; idx += 256) {
        const int key = idx >> 3, c = (idx & 7) << 3;
        half8 v = *(const half8*)(Vh + kvb + (size_t)key * HD_ + c);
        #pragma unroll
        for (int j = 0; j < 8; ++j) Vt[(c + j) * 232 + key] = v[j];
    }
    // zero Vt pad cols 197..223
    for (int idx = tid; idx < 64 * 27; idx += 256) {
        const int d = idx / 27, k = 197 + (idx - d * 27);
        Vt[d * 232 + k] = (_Float16)0;
    }
    // Q fragments direct from global (row m = lane&15 within this wave's strip)
    const int qrow = rt * 64 + wave * 16 + ln;
    const _Float16* Qp = Qh + kvb + (size_t)((qrow < N_) ? qrow : 0) * HD_ + kq * 8;
    half8 qf0 = *(const half8*)Qp;
    half8 qf1 = *(const half8*)(Qp + 32);
    __syncthreads();

    // S = Q K^T over 13 key tiles
    f32x4 acc[13] = {};
    #pragma unroll
    for (int c = 0; c < 13; ++c) {
        const _Float16* kp = &Ks[(c * 16 + ln) * 72 + kq * 8];
        half8 kf0 = *(const half8*)kp;
        half8 kf1 = *(const half8*)(kp + 32);
        acc[c] = __builtin_amdgcn_mfma_f32_16x16x32_f16(qf0, kf0, acc[c], 0, 0, 0);
        acc[c] = __builtin_amdgcn_mfma_f32_16x16x32_f16(qf1, kf1, acc[c], 0, 0, 0);
    }
    // softmax per row (lane holds rows kq*4+r, cols c*16+ln); mask cols>=197
    float inv4[4];
    #pragma unroll
    for (int r = 0; r < 4; ++r) {
        float m = -1e30f;
        #pragma unroll
        for (int c = 0; c < 13; ++c) {
            float x = ((c * 16 + ln) < N_) ? acc[c][r] : -1e30f;
            acc[c][r] = x;
            m = fmaxf(m, x);
        }
        m = fmaxf(m, __shfl_xor(m, 1)); m = fmaxf(m, __shfl_xor(m, 2));
        m = fmaxf(m, __shfl_xor(m, 4)); m = fmaxf(m, __shfl_xor(m, 8));
        float s = 0.f;
        #pragma unroll
        for (int c = 0; c < 13; ++c) { float e = __expf(acc[c][r] - m); acc[c][r] = e; s += e; }
        s += __shfl_xor(s, 1); s += __shfl_xor(s, 2);
        s += __shfl_xor(s, 4); s += __shfl_xor(s, 8);
        inv4[r] = 1.f / s;
    }
    __syncthreads();                  // all waves done reading Ks -> reuse as Pl

    // write P (fp16) into this wave's strip; cols 208..223 zero
    _Float16* Pw = Pl + wave * 16 * 232;
    #pragma unroll
    for (int c = 0; c < 13; ++c) {
        const int col = c * 16 + ln;
        #pragma unroll
        for (int r = 0; r < 4; ++r)
            Pw[(kq * 4 + r) * 232 + col] = (_Float16)(acc[c][r] * inv4[r]);
    }
    #pragma unroll
    for (int r = 0; r < 4; ++r) Pw[(kq * 4 + r) * 232 + 208 + ln] = (_Float16)0;

    // CLS-row probs for global_attn (row 0 = rt0/wave0/quad0/reg0)
    if (rt == 0 && wave == 0 && kq == 0) {
        #pragma unroll
        for (int c = 0; c < 13; ++c) {
            const int col = c * 16 + ln;
            if (col >= 1 && col < N_) P0[(size_t)bh * 196 + col - 1] = acc[c][0] * inv4[0];
        }
    }
    __syncthreads();                  // P visible (cheap safety barrier)

    // O = P V : 7 k-steps of 32 keys (pads are zeros)
    f32x4 o4[4] = {};
    for (int t = 0; t < 7; ++t) {
        half8 pf = *(const half8*)&Pw[ln * 232 + kq * 8 + 32 * t];
        #pragma unroll
        for (int n = 0; n < 4; ++n) {
            half8 vf = *(const half8*)&Vt[(n * 16 + ln) * 232 + kq * 8 + 32 * t];
            o4[n] = __builtin_amdgcn_mfma_f32_16x16x32_f16(pf, vf, o4[n], 0, 0, 0);
        }
    }
    // store O fp16 [B][N][C]
    const int g0 = rt * 64 + wave * 16 + kq * 4;
    #pragma unroll
    for (int r = 0; r < 4; ++r) {
        const int g = g0 + r;
        if (g >= N_) continue;
        _Float16* op = Oh + ((size_t)b * N_ + g) * C_ + h * HD_;
        #pragma unroll
        for (int n = 0; n < 4; ++n) op[n * 16 + ln] = (_Float16)o4[n][r];
    }
}

// ---------------------------------------------------------------------------
// global_attn[b][m] = mean_h P0[b*12+h][m]
__global__ void k_gattn(const float* __restrict__ P0, float* __restrict__ out2) {
    const int idx = blockIdx.x * blockDim.x + threadIdx.x;   // 12544 exact
    const int b = idx / (N_ - 1), m = idx - b * (N_ - 1);
    float s = 0.f;
    #pragma unroll
    for (int h = 0; h < H_; ++h) s += P0[((size_t)(b * H_ + h)) * 196 + m];
    out2[idx] = s * (1.f / H_);
}

// ---------------------------------------------------------------------------
extern "C" void kernel_launch(void* const* d_in, const int* in_sizes, int n_in,
                              void* d_out, int out_size, void* d_ws, size_t ws_size,
                              hipStream_t stream) {
    const float* x      = (const float*)d_in[0];
    const float* w_qkv  = (const float*)d_in[1];
    const float* w_proj = (const float*)d_in[2];
    const float* b_proj = (const float*)d_in[3];
    float* out = (float*)d_out;
    char* ws   = (char*)d_ws;

    if (ws_size < (size_t)WS_BYTES) {
        k_ws_too_small<<<1, 1, 0, stream>>>(out, (float)ws_size);
        return;
    }

    _Float16* Xh  = (_Float16*)(ws + XH_OFF);
    _Float16* Wqh = (_Float16*)(ws + WQH_OFF);
    _Float16* Wph = (_Float16*)(ws + WPH_OFF);
    _Float16* Qh  = (_Float16*)(ws + QH_OFF);
    _Float16* Kh  = (_Float16*)(ws + KH_OFF);
    _Float16* Vh  = (_Float16*)(ws + VH_OFF);
    _Float16* Oh  = (_Float16*)(ws + OH_OFF);
    float*    P0  = (float*)   (ws + P0_OFF);

    k_cvt_all<<<5880, 256, 0, stream>>>(x, w_qkv, w_proj, Xh, Wqh, Wph);

    k_qkv_mfma <<<dim3(18, 99), 256, 0, stream>>>(Xh, Wqh, Qh, Kh, Vh);
    k_attn     <<<dim3(4, BH_), 256, 0, stream>>>(Qh, Kh, Vh, Oh, P0);
    k_gattn    <<<dim3(49),     256, 0, stream>>>(P0, out + (size_t)M_ * C_);
    k_proj_mfma<<<dim3(6, 99),  256, 0, stream>>>(Oh, Wph, b_proj, out);
}

// Round 2
// 243.715 us; speedup vs baseline: 1.0713x; 1.0713x over previous
//
#include <hip/hip_runtime.h>
#include <math.h>

// Problem constants
#define B_   64
#define N_   197
#define C_   768
#define H_   12
#define HD_  64
#define BH_  (B_ * H_)          // 768
#define M_   (B_ * N_)          // 12608

typedef _Float16 half8 __attribute__((ext_vector_type(8)));
typedef float    f32x4 __attribute__((ext_vector_type(4)));

// Workspace byte offsets (all 16B aligned)
#define XH_OFF   0u           // 12608*768 fp16      = 19,365,888 B
#define WQH_OFF  19365888u    // 2304*768 fp16       =  3,538,944 B
#define WPH_OFF  22904832u    // 768*768 fp16        =  1,179,648 B
#define QH_OFF   24084480u    // [bh][197][64] fp16  = 19,365,888 B
#define KH_OFF   43450368u    // [bh][197][64] fp16
#define VH_OFF   62816256u    // [bh][197][64] fp16
#define OH_OFF   82182144u    // [B][N][C] fp16      = 19,365,888 B
#define P0_OFF   101548032u   // [bh][196] fp32      =    602,112 B
#define WS_BYTES 102150144u

__device__ __forceinline__ half8 h8zero() {
    half8 z;
    #pragma unroll
    for (int i = 0; i < 8; ++i) z[i] = (_Float16)0;
    return z;
}

// async 16B global -> LDS (wave-uniform LDS base + lane*16; per-lane global addr)
__device__ __forceinline__ void async16(const _Float16* g, _Float16* l) {
    __builtin_amdgcn_global_load_lds(
        (const __attribute__((address_space(1))) void*)g,
        (__attribute__((address_space(3))) void*)l,
        16, 0, 0);
}

// m204 bijective XCD-chunk swizzle: dispatch id i (lands on XCD i%8) ->
// contiguous work chunk per XCD. Requires nothing of nwg (handles nwg%8 != 0).
__device__ __forceinline__ int xcd_swz(int i, int nwg) {
    const int q = nwg >> 3, r = nwg & 7;
    const int xcd = i & 7, j = i >> 3;
    return (xcd < r ? xcd * (q + 1) : r * (q + 1) + (xcd - r) * q) + j;
}

// ---------------------------------------------------------------------------
__global__ void k_ws_too_small(float* out, float ws_bytes) { out[0] = -ws_bytes; }

// ---------------------------------------------------------------------------
// fp32 -> fp16 bulk convert, all three tensors in one launch.
__global__ __launch_bounds__(256) void k_cvt_all(const float* __restrict__ x,
                                                 const float* __restrict__ wq,
                                                 const float* __restrict__ wp,
                                                 _Float16* __restrict__ Xh,
                                                 _Float16* __restrict__ Wqh,
                                                 _Float16* __restrict__ Wph) {
    int i = blockIdx.x * blockDim.x + threadIdx.x;
    const float* src;
    _Float16*    dst;
    if (i < 1210368)      { src = x;  dst = Xh; }
    else if (i < 1431552) { src = wq; dst = Wqh; i -= 1210368; }
    else                  { src = wp; dst = Wph; i -= 1431552; }
    float4 f0 = *(const float4*)(src + (size_t)i * 8);
    float4 f1 = *(const float4*)(src + (size_t)i * 8 + 4);
    half8 h;
    h[0]=(_Float16)f0.x; h[1]=(_Float16)f0.y; h[2]=(_Float16)f0.z; h[3]=(_Float16)f0.w;
    h[4]=(_Float16)f1.x; h[5]=(_Float16)f1.y; h[6]=(_Float16)f1.z; h[7]=(_Float16)f1.w;
    *(half8*)(dst + (size_t)i * 8) = h;
}

// ---------------------------------------------------------------------------
// NT-GEMM core, fp16 inputs, m97-style global_load_lds staging (direct-to-LDS
// DMA, linear [128][32]-half tiles, 2-barrier loop). A-frag: lane holds
// A[m=lane&15][k=(lane>>4)*8+j]; C/D: col=lane&15, row=quad*4+reg.
__device__ __forceinline__ void mfma_nt_core_h(const _Float16* __restrict__ A,
                                               const _Float16* __restrict__ B,
                                               int M, int K, int m0, int n0,
                                               _Float16* As, _Float16* Bs,
                                               f32x4 (&acc)[4][4]) {
    const int tid  = threadIdx.x;
    const int wave = tid >> 6, lane = tid & 63;
    const int wr   = (wave >> 1) << 6;
    const int wc   = (wave & 1) << 6;
    const int ln   = lane & 15, kq = lane >> 4;

    // staging geometry: chunk ci = rd*256 + tid -> LDS byte ci*16
    //   row = ci>>2 (rd0: 0..63, rd1: 64..127), col halves = (ci&3)*8
    const int row0 = tid >> 2;
    const int ch0  = (tid & 3) << 3;
    int ar0 = m0 + row0;        if (ar0 >= M) ar0 = 0;   // clamp; garbage rows
    int ar1 = m0 + 64 + row0;   if (ar1 >= M) ar1 = 0;   // discarded in epilogue
    const _Float16* A0 = A + (size_t)ar0 * K + ch0;
    const _Float16* A1 = A + (size_t)ar1 * K + ch0;
    const _Float16* B0 = B + (size_t)(n0 + row0) * K + ch0;
    const _Float16* B1 = B + (size_t)(n0 + 64 + row0) * K + ch0;
    // wave-uniform LDS dest bases (halves): rd*2048 + wave*512; HW adds lane*16B
    _Float16* AsD = As + (wave << 9);
    _Float16* BsD = Bs + (wave << 9);

    for (int k0 = 0; k0 < K; k0 += 32) {
        __syncthreads();                   // prior frag reads done before overwrite
        async16(A0 + k0, AsD);
        async16(A1 + k0, AsD + 2048);
        async16(B0 + k0, BsD);
        async16(B1 + k0, BsD + 2048);
        __syncthreads();                   // compiler drains vmcnt(0) before barrier

        half8 af[4], bf[4];
        #pragma unroll
        for (int t = 0; t < 4; ++t) {
            af[t] = *(const half8*)&As[(wr + t * 16 + ln) * 32 + kq * 8];
            bf[t] = *(const half8*)&Bs[(wc + t * 16 + ln) * 32 + kq * 8];
        }
        #pragma unroll
        for (int i = 0; i < 4; ++i)
            #pragma unroll
            for (int j = 0; j < 4; ++j)
                acc[i][j] = __builtin_amdgcn_mfma_f32_16x16x32_f16(af[i], bf[j], acc[i][j], 0, 0, 0);
    }
}

// ---------------------------------------------------------------------------
// qkv = x @ w_qkv^T (fp16 MFMA); scatter epilogue -> Qh(x0.125)/Kh/Vh fp16
// XCD-chunk swizzled grid: consecutive works share the A-tile (18 n-tiles).
__global__ __launch_bounds__(256) void k_qkv_mfma(const _Float16* __restrict__ Xh,
                                                  const _Float16* __restrict__ Wq,
                                                  _Float16* __restrict__ Qh,
                                                  _Float16* __restrict__ Kh,
                                                  _Float16* __restrict__ Vh) {
    __shared__ _Float16 As[128 * 32];
    __shared__ _Float16 Bs[128 * 32];
    const int work = xcd_swz(blockIdx.y * 18 + blockIdx.x, 18 * 99);
    const int m0 = (work / 18) << 7;
    const int n0 = (work % 18) << 7;
    f32x4 acc[4][4] = {};
    mfma_nt_core_h(Xh, Wq, M_, C_, m0, n0, As, Bs, acc);

    const int lane = threadIdx.x & 63;
    const int wave = threadIdx.x >> 6;
    const int wr = (wave >> 1) << 6, wc = (wave & 1) << 6;
    const int ln = lane & 15, kq = lane >> 4;

    // hoisted per-nt scatter targets: d fixed per thread per nt
    _Float16* basep[4];
    float     scl[4];
    #pragma unroll
    for (int nt = 0; nt < 4; ++nt) {
        const int d  = n0 + wc + nt * 16 + ln;
        const int t3 = d / C_;
        const int rr = d - t3 * C_;
        const int h  = rr >> 6;
        const int e  = rr & 63;
        _Float16* t = (t3 == 0) ? Qh : (t3 == 1) ? Kh : Vh;
        basep[nt] = t + (size_t)h * N_ * HD_ + e;
        scl[nt]   = (t3 == 0) ? 0.125f : 1.f;
    }
    #pragma unroll
    for (int mt = 0; mt < 4; ++mt) {
        #pragma unroll
        for (int i = 0; i < 4; ++i) {
            const int m = m0 + wr + mt * 16 + kq * 4 + i;
            if (m >= M_) continue;
            const int b = m / N_;
            const int n = m - b * N_;
            const size_t rowoff = ((size_t)b * H_ * N_ + n) * HD_;
            #pragma unroll
            for (int nt = 0; nt < 4; ++nt)
                basep[nt][rowoff] = (_Float16)(acc[mt][nt][i] * scl[nt]);
        }
    }
}

// ---------------------------------------------------------------------------
// out = O @ w_proj^T + b_proj (fp16 MFMA, fp32 out), XCD-chunk swizzled grid
__global__ __launch_bounds__(256) void k_proj_mfma(const _Float16* __restrict__ Oh,
                                                   const _Float16* __restrict__ Wp,
                                                   const float* __restrict__ bias,
                                                   float* __restrict__ out) {
    __shared__ _Float16 As[128 * 32];
    __shared__ _Float16 Bs[128 * 32];
    const int work = xcd_swz(blockIdx.y * 6 + blockIdx.x, 6 * 99);
    const int m0 = (work / 6) << 7;
    const int n0 = (work % 6) << 7;
    f32x4 acc[4][4] = {};
    mfma_nt_core_h(Oh, Wp, M_, C_, m0, n0, As, Bs, acc);

    const int lane = threadIdx.x & 63;
    const int wave = threadIdx.x >> 6;
    const int wr = (wave >> 1) << 6, wc = (wave & 1) << 6;
    const int ln = lane & 15, kq = lane >> 4;
    float bv[4];
    #pragma unroll
    for (int nt = 0; nt < 4; ++nt) bv[nt] = bias[n0 + wc + nt * 16 + ln];
    #pragma unroll
    for (int mt = 0; mt < 4; ++mt) {
        #pragma unroll
        for (int i = 0; i < 4; ++i) {
            const int m = m0 + wr + mt * 16 + kq * 4 + i;
            if (m >= M_) continue;
            #pragma unroll
            for (int nt = 0; nt < 4; ++nt)
                out[(size_t)m * C_ + n0 + wc + nt * 16 + ln] = acc[mt][nt][i] + bv[nt];
        }
    }
}

// ---------------------------------------------------------------------------
// Fused attention: per (row-tile rt of 64, bh): S=QK^T -> softmax -> O=PV.
// LDS: Ks 208x72 (S phase) aliased by Pl 4x16x232 (PV phase); Vt 64x232.
// XCD-chunked so the 4 rt-blocks of one bh share K/V in the same L2.
__global__ __launch_bounds__(256) void k_attn(const _Float16* __restrict__ Qh,
                                              const _Float16* __restrict__ Kh,
                                              const _Float16* __restrict__ Vh,
                                              _Float16* __restrict__ Oh,
                                              float* __restrict__ P0) {
    __shared__ _Float16 lds[29824];
    _Float16* Ks = lds;            // 208*72 = 14976 halves
    _Float16* Pl = lds;            // 4*16*232 = 14848 halves (aliases Ks)
    _Float16* Vt = lds + 14976;    // 64*232  = 14848 halves

    const int work = xcd_swz(blockIdx.y * 4 + blockIdx.x, 4 * BH_);
    const int bh = work >> 2, rt = work & 3;
    const int b = bh / H_, h = bh - b * H_;
    const int tid = threadIdx.x, wave = tid >> 6, lane = tid & 63;
    const int ln = lane & 15, kq = lane >> 4;
    const size_t kvb = (size_t)bh * N_ * HD_;

    // stage K rows -> Ks[key*72 + d]; keys 197..207 zeroed
    for (int idx = tid; idx < 208 * 8; idx += 256) {
        const int key = idx >> 3, c = (idx & 7) << 3;
        half8 v = (key < N_) ? *(const half8*)(Kh + kvb + (size_t)key * HD_ + c) : h8zero();
        *(half8*)&Ks[key * 72 + c] = v;
    }
    // stage V transposed -> Vt[d*232 + key]
    for (int idx = tid; idx < 197 * 8; idx += 256) {
        const int key = idx >> 3, c = (idx & 7) << 3;
        half8 v = *(const half8*)(Vh + kvb + (size_t)key * HD_ + c);
        #pragma unroll
        for (int j = 0; j < 8; ++j) Vt[(c + j) * 232 + key] = v[j];
    }
    // zero Vt pad cols 197..223
    for (int idx = tid; idx < 64 * 27; idx += 256) {
        const int d = idx / 27, k = 197 + (idx - d * 27);
        Vt[d * 232 + k] = (_Float16)0;
    }
    // Q fragments direct from global (row m = lane&15 within this wave's strip)
    const int qrow = rt * 64 + wave * 16 + ln;
    const _Float16* Qp = Qh + kvb + (size_t)((qrow < N_) ? qrow : 0) * HD_ + kq * 8;
    half8 qf0 = *(const half8*)Qp;
    half8 qf1 = *(const half8*)(Qp + 32);
    __syncthreads();

    // S = Q K^T over 13 key tiles
    f32x4 acc[13] = {};
    __builtin_amdgcn_s_setprio(1);
    #pragma unroll
    for (int c = 0; c < 13; ++c) {
        const _Float16* kp = &Ks[(c * 16 + ln) * 72 + kq * 8];
        half8 kf0 = *(const half8*)kp;
        half8 kf1 = *(const half8*)(kp + 32);
        acc[c] = __builtin_amdgcn_mfma_f32_16x16x32_f16(qf0, kf0, acc[c], 0, 0, 0);
        acc[c] = __builtin_amdgcn_mfma_f32_16x16x32_f16(qf1, kf1, acc[c], 0, 0, 0);
    }
    __builtin_amdgcn_s_setprio(0);
    // softmax per row (lane holds rows kq*4+r, cols c*16+ln); mask cols>=197
    float inv4[4];
    #pragma unroll
    for (int r = 0; r < 4; ++r) {
        float m = -1e30f;
        #pragma unroll
        for (int c = 0; c < 13; ++c) {
            float x = ((c * 16 + ln) < N_) ? acc[c][r] : -1e30f;
            acc[c][r] = x;
            m = fmaxf(m, x);
        }
        m = fmaxf(m, __shfl_xor(m, 1)); m = fmaxf(m, __shfl_xor(m, 2));
        m = fmaxf(m, __shfl_xor(m, 4)); m = fmaxf(m, __shfl_xor(m, 8));
        float s = 0.f;
        #pragma unroll
        for (int c = 0; c < 13; ++c) { float e = __expf(acc[c][r] - m); acc[c][r] = e; s += e; }
        s += __shfl_xor(s, 1); s += __shfl_xor(s, 2);
        s += __shfl_xor(s, 4); s += __shfl_xor(s, 8);
        inv4[r] = 1.f / s;
    }
    __syncthreads();                  // all waves done reading Ks -> reuse as Pl

    // write P (fp16) into this wave's strip; cols 208..223 zero
    _Float16* Pw = Pl + wave * 16 * 232;
    #pragma unroll
    for (int c = 0; c < 13; ++c) {
        const int col = c * 16 + ln;
        #pragma unroll
        for (int r = 0; r < 4; ++r)
            Pw[(kq * 4 + r) * 232 + col] = (_Float16)(acc[c][r] * inv4[r]);
    }
    #pragma unroll
    for (int r = 0; r < 4; ++r) Pw[(kq * 4 + r) * 232 + 208 + ln] = (_Float16)0;

    // CLS-row probs for global_attn (row 0 = rt0/wave0/quad0/reg0)
    if (rt == 0 && wave == 0 && kq == 0) {
        #pragma unroll
        for (int c = 0; c < 13; ++c) {
            const int col = c * 16 + ln;
            if (col >= 1 && col < N_) P0[(size_t)bh * 196 + col - 1] = acc[c][0] * inv4[0];
        }
    }
    __syncthreads();                  // P visible (cheap safety barrier)

    // O = P V : 7 k-steps of 32 keys (pads are zeros)
    f32x4 o4[4] = {};
    __builtin_amdgcn_s_setprio(1);
    for (int t = 0; t < 7; ++t) {
        half8 pf = *(const half8*)&Pw[ln * 232 + kq * 8 + 32 * t];
        #pragma unroll
        for (int n = 0; n < 4; ++n) {
            half8 vf = *(const half8*)&Vt[(n * 16 + ln) * 232 + kq * 8 + 32 * t];
            o4[n] = __builtin_amdgcn_mfma_f32_16x16x32_f16(pf, vf, o4[n], 0, 0, 0);
        }
    }
    __builtin_amdgcn_s_setprio(0);
    // store O fp16 [B][N][C]
    const int g0 = rt * 64 + wave * 16 + kq * 4;
    #pragma unroll
    for (int r = 0; r < 4; ++r) {
        const int g = g0 + r;
        if (g >= N_) continue;
        _Float16* op = Oh + ((size_t)b * N_ + g) * C_ + h * HD_;
        #pragma unroll
        for (int n = 0; n < 4; ++n) op[n * 16 + ln] = (_Float16)o4[n][r];
    }
}

// ---------------------------------------------------------------------------
// global_attn[b][m] = mean_h P0[b*12+h][m]
__global__ void k_gattn(const float* __restrict__ P0, float* __restrict__ out2) {
    const int idx = blockIdx.x * blockDim.x + threadIdx.x;   // 12544 exact
    const int b = idx / (N_ - 1), m = idx - b * (N_ - 1);
    float s = 0.f;
    #pragma unroll
    for (int h = 0; h < H_; ++h) s += P0[((size_t)(b * H_ + h)) * 196 + m];
    out2[idx] = s * (1.f / H_);
}

// ---------------------------------------------------------------------------
extern "C" void kernel_launch(void* const* d_in, const int* in_sizes, int n_in,
                              void* d_out, int out_size, void* d_ws, size_t ws_size,
                              hipStream_t stream) {
    const float* x      = (const float*)d_in[0];
    const float* w_qkv  = (const float*)d_in[1];
    const float* w_proj = (const float*)d_in[2];
    const float* b_proj = (const float*)d_in[3];
    float* out = (float*)d_out;
    char* ws   = (char*)d_ws;

    if (ws_size < (size_t)WS_BYTES) {
        k_ws_too_small<<<1, 1, 0, stream>>>(out, (float)ws_size);
        return;
    }

    _Float16* Xh  = (_Float16*)(ws + XH_OFF);
    _Float16* Wqh = (_Float16*)(ws + WQH_OFF);
    _Float16* Wph = (_Float16*)(ws + WPH_OFF);
    _Float16* Qh  = (_Float16*)(ws + QH_OFF);
    _Float16* Kh  = (_Float16*)(ws + KH_OFF);
    _Float16* Vh  = (_Float16*)(ws + VH_OFF);
    _Float16* Oh  = (_Float16*)(ws + OH_OFF);
    float*    P0  = (float*)   (ws + P0_OFF);

    k_cvt_all<<<5880, 256, 0, stream>>>(x, w_qkv, w_proj, Xh, Wqh, Wph);

    k_qkv_mfma <<<dim3(18, 99), 256, 0, stream>>>(Xh, Wqh, Qh, Kh, Vh);
    k_attn     <<<dim3(4, BH_), 256, 0, stream>>>(Qh, Kh, Vh, Oh, P0);
    k_gattn    <<<dim3(49),     256, 0, stream>>>(P0, out + (size_t)M_ * C_);
    k_proj_mfma<<<dim3(6, 99),  256, 0, stream>>>(Oh, Wph, b_proj, out);
}